// Round 12
// baseline (636.123 us; speedup 1.0000x reference)
//
#include <hip/hip_runtime.h>
#include <stdint.h>

// LSTM: B=65536, T=28, IN=28, H=128. Final hidden [B,H] output.
// ROUND 12 = R11 (388us: 8-wave/512t, wave owns 16 cols x 4 gates, 80 weight
// regs persistent, log2e pre-scaled weights, bias in K-slot 156, c in regs,
// parity A-prefetch, algebraic 8-trans epilogue, (512,4)) + ONE change:
//  T14 ASYNC-STAGE SPLIT: next-x global load ISSUED at step top, LDS write
//  deferred to just before the barrier (~2000cy of MFMA+epilogue in between
//  -> HBM latency hidden). R11 loaded+wrote at step top -> s_waitcnt vmcnt(0)
//  right after the barrier = ~500-900cy exposed stall for waves 0-3 every
//  step, absorbed by all 8 waves at the barrier (~12-20% of wall time).
//  fp32 variant: f2bf conversion also moved to the write site.
// Occupancy map (measured): (512,8) spills weights (R7); (512,4) = optimum
// (R8); (512,2) full residency but TLP-starved (R10).
// Lessons: no volatile-asm reg pins (R5); no cvt_pk-asm/operand-swap (R9).

#define T_STEPS   28
#define HDIM      128
#define KIN       156            // H + IN
#define MB        32             // batch rows per block
#define KSTEPS    5              // K=160: 4x32 (h) + 1x32 (x: 28 real + bias@28 + 3 pad)
#define HLDS_ST   136            // h_lds row stride in shorts (128 + 8 pad)
#define XLDS_ST   40             // x_lds row stride in shorts (32 + 8 pad)
#define L2E       1.4426950408889634f

#define WS_WOFF   1024           // byte offset of packed weights in d_ws

typedef __attribute__((ext_vector_type(8))) short  short8;
typedef __attribute__((ext_vector_type(4))) float  floatx4;

union Frag { short8 f; uint2 u2[2]; unsigned short s[8]; };
union Pk4  { uint2 u2; unsigned short s[4]; };

__device__ __forceinline__ float bf2f(unsigned short v) {
    union { uint32_t u; float f; } c; c.u = ((uint32_t)v) << 16; return c.f;
}
__device__ __forceinline__ unsigned short f2bf(float x) {
    union { float f; uint32_t u; } c; c.f = x;          // RNE bf16 (finite inputs)
    return (unsigned short)((c.u + 0x7FFFu + ((c.u >> 16) & 1u)) >> 16);
}
__device__ __forceinline__ float fast_rcp(float x) { return __builtin_amdgcn_rcpf(x); }
__device__ __forceinline__ float exp2_(float x)    { return __builtin_amdgcn_exp2f(x); }

// bf16 |W_f| <= 0.08 -> exponent field <= 123 always. fp32 read as shorts:
// mantissa halves ~uniform -> exponent field >= 127 with p~0.5/short.
__global__ void detect_dtype(const unsigned short* __restrict__ wf, int* __restrict__ flag) {
    const int lane = threadIdx.x;
    bool big = false;
    #pragma unroll
    for (int i = 0; i < 4; ++i) {
        unsigned e = (wf[lane * 4 + i] >> 7) & 0xFFu;
        if (e >= 127u) big = true;
    }
    const int isfp32 = __any(big) ? 1 : 0;
    if (lane == 0) *flag = isfp32;
}

// One-shot: pack W[4][128][156] -> bf16 per-(wave,ks,lane) fragments, values
// PRE-SCALED (f,i,o: *log2e; n: *2log2e). Bias (same scale) lands in K-slot
// 156 (ks=4,q=3,e=4); slots 157..159 zero.
//   chunk = wv*5+ks (2048 shorts); idx within: ln(6b) g(2b) e(3b)
//   value = SCALE[g] * W[g][wv*16 + (ln&15)][ks*32 + (ln>>4)*8 + e]
// Grid: 320 x 256 = 81920 shorts.
template <bool FP32>
__global__ void pack_weights(const void* __restrict__ Wf_, const void* __restrict__ bf_,
                             const void* __restrict__ Wi_, const void* __restrict__ bi_,
                             const void* __restrict__ Wc_, const void* __restrict__ bc_,
                             const void* __restrict__ Wo_, const void* __restrict__ bo_,
                             void* __restrict__ ws, const int* __restrict__ flag)
{
    if (*flag != (FP32 ? 1 : 0)) return;
    unsigned short* wpk = (unsigned short*)((char*)ws + WS_WOFF);

    const int gid = blockIdx.x * 256 + threadIdx.x;        // 0..81919
    const int e   = gid & 7;
    const int g   = (gid >> 3) & 3;
    const int ln  = (gid >> 5) & 63;
    const int blk = gid >> 11;                             // wv*5 + ks, 0..39
    const int ks  = blk % KSTEPS;
    const int wv  = blk / KSTEPS;
    const int n   = wv * 16 + (ln & 15);
    const int k   = ks * 32 + (ln >> 4) * 8 + e;
    const void* Wg = (g == 0) ? Wf_ : (g == 1) ? Wi_ : (g == 2) ? Wc_ : Wo_;
    const void* bg = (g == 0) ? bf_ : (g == 1) ? bi_ : (g == 2) ? bc_ : bo_;
    const float scale = (g == 2) ? 2.0f * L2E : L2E;

    unsigned short v = 0;
    if (k < KIN) {
        float w;
        if constexpr (FP32) w = ((const float*)Wg)[n * KIN + k];
        else                w = bf2f(((const unsigned short*)Wg)[n * KIN + k]);
        v = f2bf(w * scale);
    } else if (k == KIN) {                                  // bias slot (A=1.0)
        float b;
        if constexpr (FP32) b = ((const float*)bg)[n];
        else                b = bf2f(((const unsigned short*)bg)[n]);
        v = f2bf(b * scale);
    }
    wpk[gid] = v;
}

template <bool FP32>
__global__ __launch_bounds__(512, 4)
void lstm_fused(const void* __restrict__ x_, const void* __restrict__ ws,
                void* __restrict__ out_, const int* __restrict__ flag)
{
    if (*flag != (FP32 ? 1 : 0)) return;   // wrong-dtype variant: uniform exit

    __shared__ __align__(16) unsigned short h_lds[2][MB * HLDS_ST];   // 17408 B
    __shared__ __align__(16) unsigned short x_lds[2][MB * XLDS_ST];   //  5120 B

    const int tid  = threadIdx.x;
    const int wv   = tid >> 6;     // wave 0..7: owns output cols [16wv, 16wv+16)
    const int lane = tid & 63;
    const int q    = lane >> 4;    // quad
    const int cc   = lane & 15;
    const int b0   = blockIdx.x * MB;

    const unsigned short* wpk = (const unsigned short*)((const char*)ws + WS_WOFF);

    // ---- persistent weight B-fragments: 4 gates x 5 ks x 4 regs = 80.
    Frag bfr[4][KSTEPS];
    #pragma unroll
    for (int ks = 0; ks < KSTEPS; ++ks)
        #pragma unroll
        for (int g = 0; g < 4; ++g)
            bfr[g][ks].f = *(const short8*)(wpk + (size_t)(wv * KSTEPS + ks) * 2048
                                                + lane * 32 + g * 8);

    // zero h buf0 (h0=0); x pads: slot 28 = bf16(1.0) (bias A-column),
    // slots 29..39 = 0 forever.
    for (int i = tid; i < MB * HLDS_ST; i += 512) h_lds[0][i] = 0;
    for (int i = tid; i < MB * XLDS_ST; i += 512) {
        const unsigned short v = ((i % XLDS_ST) == 28) ? (unsigned short)0x3F80u
                                                       : (unsigned short)0u;
        x_lds[0][i] = v; x_lds[1][i] = v;
    }

    // staging geometry: 7 threads/row, 4 elems each (224 of 512 threads)
    const int  srow     = tid / 7, ssub = tid % 7;
    const bool is_stager = (tid < 224);

    // initial x tile (t=0): load + write immediately (covered by weight loads)
    if (is_stager) {
        const size_t off = (size_t)(b0 + srow) * (T_STEPS * 28) + 0 * 28 + ssub * 4;
        Pk4 pk;
        if constexpr (FP32) {
            float4 v = *(const float4*)((const float*)x_ + off);
            pk.s[0] = f2bf(v.x); pk.s[1] = f2bf(v.y);
            pk.s[2] = f2bf(v.z); pk.s[3] = f2bf(v.w);
        } else {
            pk.u2 = *(const uint2*)((const unsigned short*)x_ + off);
        }
        *(uint2*)&x_lds[0][srow * XLDS_ST + ssub * 4] = pk.u2;
    }

    // ---- cell state in registers: thread owns col j = wv*16+cc, rows
    // mrow = mt*16 + q*4 + r -> c_st[mt][r], 8 VGPRs.
    float c_st[2][4];
    #pragma unroll
    for (int mt = 0; mt < 2; ++mt)
        #pragma unroll
        for (int r = 0; r < 4; ++r) c_st[mt][r] = 0.0f;

    __syncthreads();

    int cur = 0;
    #pragma unroll 1
    for (int t = 0; t < T_STEPS; ++t) {
        // ---- T14 stage split, phase 1: ISSUE next-x load (no use until the
        // write at the bottom -> waitcnt lands after ~2000cy of compute).
        const bool do_stage = is_stager && (t + 1 < T_STEPS);
        float4 xf;   // fp32 path: raw data rides in regs, converted at write
        Pk4    xp;   // bf16 path
        if (do_stage) {
            const size_t off = (size_t)(b0 + srow) * (T_STEPS * 28) + (t + 1) * 28 + ssub * 4;
            if constexpr (FP32) xf = *(const float4*)((const float*)x_ + off);
            else                xp.u2 = *(const uint2*)((const unsigned short*)x_ + off);
        }

        #pragma unroll
        for (int mt = 0; mt < 2; ++mt) {
            // A fragments: parity double-buffer across ks (8 regs live)
            Frag a[2];
            a[0].f = *(const short8*)&h_lds[cur][(mt * 16 + cc) * HLDS_ST + q * 8];

            floatx4 acc[4];
            #pragma unroll
            for (int g = 0; g < 4; ++g)
                acc[g] = (floatx4){0.0f, 0.0f, 0.0f, 0.0f};   // bias via K=156

            #pragma unroll
            for (int ks = 0; ks < KSTEPS; ++ks) {
                if (ks + 1 < KSTEPS) {
                    if (ks + 1 < 4)
                        a[(ks + 1) & 1].f = *(const short8*)
                            &h_lds[cur][(mt * 16 + cc) * HLDS_ST + (ks + 1) * 32 + q * 8];
                    else
                        a[(ks + 1) & 1].f = *(const short8*)
                            &x_lds[cur][(mt * 16 + cc) * XLDS_ST + q * 8];
                }
                #pragma unroll
                for (int g = 0; g < 4; ++g)
                    acc[g] = __builtin_amdgcn_mfma_f32_16x16x32_bf16(
                        a[ks & 1].f, bfr[g][ks].f, acc[g], 0, 0, 0);
            }

            // ---- algebraic epilogue: 5 exp2 + 3 rcp per output.
            //   f          = 1/(1+ef)
            //   i*tanh(n)  = (en-1) / ((1+ei)(1+en))
            //   o*tanh(c') = (e2c-1) / ((1+eo)(e2c+1))
            // acc pre-scaled: f,i,o by log2e; n by 2*log2e.
            const int j = wv * 16 + cc;
            #pragma unroll
            for (int r = 0; r < 4; ++r) {
                const int mrow = mt * 16 + q * 4 + r;
                const float ef  = exp2_(-acc[0][r]);
                const float ei  = exp2_(-acc[1][r]);
                const float en  = exp2_( acc[2][r]);
                const float eo  = exp2_(-acc[3][r]);
                const float fv  = fast_rcp(1.0f + ef);
                const float rin = fast_rcp((1.0f + ei) * (1.0f + en));
                const float inn = (en - 1.0f) * rin;
                const float cn  = fmaf(c_st[mt][r], fv, inn);
                c_st[mt][r] = cn;
                const float e2c = exp2_((2.0f * L2E) * cn);
                const float rdo = fast_rcp((1.0f + eo) * (e2c + 1.0f));
                const float hv  = (e2c - 1.0f) * rdo;
                h_lds[cur ^ 1][mrow * HLDS_ST + j] = f2bf(hv);
                if (t == T_STEPS - 1) {
                    const size_t oi = (size_t)(b0 + mrow) * HDIM + j;
                    if constexpr (FP32) ((float*)out_)[oi] = hv;
                    else                ((unsigned short*)out_)[oi] = f2bf(hv);
                }
            }
        }

        // ---- T14 stage split, phase 2: write staged x (latency now hidden)
        if (do_stage) {
            Pk4 pk;
            if constexpr (FP32) {
                pk.s[0] = f2bf(xf.x); pk.s[1] = f2bf(xf.y);
                pk.s[2] = f2bf(xf.z); pk.s[3] = f2bf(xf.w);
            } else {
                pk = xp;
            }
            *(uint2*)&x_lds[cur ^ 1][srow * XLDS_ST + ssub * 4] = pk.u2;
        }
        __syncthreads();     // single barrier: publishes h[cur^1] and x[cur^1]
        cur ^= 1;
    }
}

extern "C" void kernel_launch(void* const* d_in, const int* in_sizes, int n_in,
                              void* d_out, int out_size, void* d_ws, size_t ws_size,
                              hipStream_t stream) {
    int* flag = (int*)d_ws;
    detect_dtype<<<dim3(1), dim3(64), 0, stream>>>((const unsigned short*)d_in[1], flag);

    pack_weights<false><<<dim3(320), dim3(256), 0, stream>>>(
        d_in[1], d_in[2], d_in[3], d_in[4], d_in[5], d_in[6], d_in[7], d_in[8], d_ws, flag);
    pack_weights<true><<<dim3(320), dim3(256), 0, stream>>>(
        d_in[1], d_in[2], d_in[3], d_in[4], d_in[5], d_in[6], d_in[7], d_in[8], d_ws, flag);

    lstm_fused<false><<<dim3(65536 / MB), dim3(512), 0, stream>>>(d_in[0], d_ws, d_out, flag);
    lstm_fused<true><<<dim3(65536 / MB), dim3(512), 0, stream>>>(d_in[0], d_ws, d_out, flag);
}